// Round 1
// baseline (191.849 us; speedup 1.0000x reference)
//
#include <hip/hip_runtime.h>
#include <hip/hip_bf16.h>

#define BQ 64
#define KN 256
#define DD 1024
#define HH 2
#define MT (BQ*KN)

typedef __attribute__((ext_vector_type(8))) short short8;
typedef __attribute__((ext_vector_type(4))) float f32x4;

__device__ __forceinline__ ushort f2b(float f) {
  union { float f; unsigned u; } v; v.f = f;
  unsigned u = v.u;
  return (ushort)((u + 0x7fffu + ((u >> 16) & 1u)) >> 16);
}
__device__ __forceinline__ float b2f(ushort h) {
  union { unsigned u; float f; } v; v.u = ((unsigned)h) << 16;
  return v.f;
}

// ---------------- K0: W (DxD f32) -> WTb (DxD bf16, transposed: WTb[n][k] = W[k][n])
__global__ __launch_bounds__(256) void k_wT(const float* __restrict__ W, ushort* __restrict__ WTb) {
  __shared__ float t[32][33];
  int tx = threadIdx.x, ty = threadIdx.y;
  int x = blockIdx.x * 32 + tx;          // col of W
  int y0 = blockIdx.y * 32 + ty;         // row of W
  for (int i = 0; i < 32; i += 8)
    t[ty + i][tx] = W[(size_t)(y0 + i) * DD + x];
  __syncthreads();
  int xo = blockIdx.y * 32 + tx;         // col of WTb (= k)
  int yo = blockIdx.x * 32 + ty;         // row of WTb (= n)
  for (int i = 0; i < 32; i += 8)
    WTb[(size_t)(yo + i) * DD + xo] = f2b(t[tx][ty + i]);
}

// ---------------- K1: h = x @ W  (M=16384, N=1024, K=1024), bf16 MFMA, out bf16
#define BM 128
#define BN 128
#define BK 32
#define LDK 40   // padded K-stride in LDS (bf16 elems); 80B rows keep 16B alignment

__global__ __launch_bounds__(256) void k_gemm_h(const float* __restrict__ x,
                                                const ushort* __restrict__ WTb,
                                                ushort* __restrict__ hb) {
  __shared__ ushort As[BM][LDK];
  __shared__ ushort Bs[BN][LDK];
  const int tid = threadIdx.x;
  const int bm = blockIdx.x;   // 0..127
  const int bn = blockIdx.y;   // 0..7
  const int wave = tid >> 6, lane = tid & 63;
  const int wm = (wave >> 1) * 64, wn = (wave & 1) * 64;
  const int r16 = lane & 15, kq = (lane >> 4) * 8;
  f32x4 acc[4][4] = {};

  for (int kt = 0; kt < DD; kt += BK) {
    // A tile: 128x32 f32 -> bf16 LDS. 1024 float4 chunks, 4/thread.
    for (int it = 0; it < 4; ++it) {
      int c = tid + 256 * it;
      int row = c >> 3, kp = (c & 7) * 4;
      float4 v = *reinterpret_cast<const float4*>(&x[(size_t)(bm * BM + row) * DD + kt + kp]);
      ushort4 bvec;
      bvec.x = f2b(v.x); bvec.y = f2b(v.y); bvec.z = f2b(v.z); bvec.w = f2b(v.w);
      *reinterpret_cast<ushort4*>(&As[row][kp]) = bvec;
    }
    // B tile: WTb rows (n-major, k contiguous). 512 chunks of 8 bf16, 2/thread.
    for (int it = 0; it < 2; ++it) {
      int c = tid + 256 * it;
      int n = c >> 2, kp = (c & 3) * 8;
      short8 v = *reinterpret_cast<const short8*>(&WTb[(size_t)(bn * BN + n) * DD + kt + kp]);
      *reinterpret_cast<short8*>(&Bs[n][kp]) = v;
    }
    __syncthreads();
    short8 af[4], bf[4];
    for (int mf = 0; mf < 4; ++mf)
      af[mf] = *reinterpret_cast<const short8*>(&As[wm + mf * 16 + r16][kq]);
    for (int nf = 0; nf < 4; ++nf)
      bf[nf] = *reinterpret_cast<const short8*>(&Bs[wn + nf * 16 + r16][kq]);
    for (int mf = 0; mf < 4; ++mf)
      for (int nf = 0; nf < 4; ++nf)
        acc[mf][nf] = __builtin_amdgcn_mfma_f32_16x16x32_bf16(af[mf], bf[nf], acc[mf][nf], 0, 0, 0);
    __syncthreads();
  }
  // epilogue: D[row][col], row = mf*16 + (lane>>4)*4 + r, col = nf*16 + (lane&15)
  for (int mf = 0; mf < 4; ++mf)
    for (int nf = 0; nf < 4; ++nf) {
      int col = bn * BN + wn + nf * 16 + r16;
      int rowb = bm * BM + wm + mf * 16 + (lane >> 4) * 4;
      for (int r = 0; r < 4; ++r)
        hb[(size_t)(rowb + r) * DD + col] = f2b(acc[mf][nf][r]);
    }
}

// ---------------- K2: f_i[b,h,k] = h[b,k,:]·a[h,0:D], f_j = h·a[h,D:2D]
__global__ __launch_bounds__(256) void k_f(const ushort* __restrict__ hb,
                                           const float* __restrict__ a,
                                           float* __restrict__ fi, float* __restrict__ fj) {
  int wave = threadIdx.x >> 6, lane = threadIdx.x & 63;
  size_t row = (size_t)blockIdx.x * 4 + wave;   // b*KN + k
  const ushort* hr = hb + row * DD;
  float acc0 = 0.f, acc1 = 0.f, acc2 = 0.f, acc3 = 0.f;
  for (int d0 = lane * 8; d0 < DD; d0 += 512) {
    short8 v = *reinterpret_cast<const short8*>(&hr[d0]);
    for (int e = 0; e < 8; ++e) {
      float hv = b2f((ushort)v[e]);
      int d = d0 + e;
      acc0 += hv * a[d];                 // h0 src
      acc1 += hv * a[2 * DD + d];        // h1 src
      acc2 += hv * a[DD + d];            // h0 dst
      acc3 += hv * a[3 * DD + d];        // h1 dst
    }
  }
  for (int off = 32; off; off >>= 1) {
    acc0 += __shfl_down(acc0, off);
    acc1 += __shfl_down(acc1, off);
    acc2 += __shfl_down(acc2, off);
    acc3 += __shfl_down(acc3, off);
  }
  if (lane == 0) {
    int b = (int)(row / KN), k = (int)(row % KN);
    fi[(b * HH + 0) * KN + k] = acc0;
    fi[(b * HH + 1) * KN + k] = acc1;
    fj[(b * HH + 0) * KN + k] = acc2;
    fj[(b * HH + 1) * KN + k] = acc3;
  }
}

// ---------------- K3: masked leaky softmax, head-mean -> Pbar bf16
__global__ __launch_bounds__(256) void k_attn(const float* __restrict__ fi, const float* __restrict__ fj,
                                              const int* __restrict__ adj, ushort* __restrict__ Pb) {
  const float NEGINF = -__builtin_huge_valf();
  int i = blockIdx.x, b = blockIdx.y, j = threadIdx.x;
  bool msk = adj[i * KN + j] != 0;
  float e0 = fi[(b * HH + 0) * KN + i] + fj[(b * HH + 0) * KN + j];
  float e1 = fi[(b * HH + 1) * KN + i] + fj[(b * HH + 1) * KN + j];
  e0 = e0 >= 0.f ? e0 : 0.2f * e0;
  e1 = e1 >= 0.f ? e1 : 0.2f * e1;
  if (!msk) { e0 = NEGINF; e1 = NEGINF; }
  __shared__ float red0[4], red1[4];
  int wave = j >> 6, lane = j & 63;
  float m0 = e0, m1 = e1;
  for (int off = 32; off; off >>= 1) {
    m0 = fmaxf(m0, __shfl_down(m0, off));
    m1 = fmaxf(m1, __shfl_down(m1, off));
  }
  if (lane == 0) { red0[wave] = m0; red1[wave] = m1; }
  __syncthreads();
  m0 = fmaxf(fmaxf(red0[0], red0[1]), fmaxf(red0[2], red0[3]));
  m1 = fmaxf(fmaxf(red1[0], red1[1]), fmaxf(red1[2], red1[3]));
  float p0 = (m0 == NEGINF) ? 0.f : __expf(e0 - m0);  // masked lane: exp(-inf)=0
  float p1 = (m1 == NEGINF) ? 0.f : __expf(e1 - m1);
  __syncthreads();
  float s0 = p0, s1 = p1;
  for (int off = 32; off; off >>= 1) {
    s0 += __shfl_down(s0, off);
    s1 += __shfl_down(s1, off);
  }
  if (lane == 0) { red0[wave] = s0; red1[wave] = s1; }
  __syncthreads();
  s0 = red0[0] + red0[1] + red0[2] + red0[3];
  s1 = red1[0] + red1[1] + red1[2] + red1[3];
  float r0 = s0 > 0.f ? p0 / s0 : 0.f;
  float r1 = s1 > 0.f ? p1 / s1 : 0.f;
  Pb[((size_t)b * KN + i) * KN + j] = f2b(0.5f * (r0 + r1));
}

// ---------------- K4: out0[b] = Pbar[b] @ h[b], + x residual -> ypre bf16
__global__ __launch_bounds__(256) void k_gemm_o(const ushort* __restrict__ Pb,
                                                const ushort* __restrict__ hb,
                                                const float* __restrict__ x,
                                                ushort* __restrict__ ypre) {
  __shared__ ushort As[BM][LDK];
  __shared__ ushort Bs[BN][LDK];
  const int b = blockIdx.z;
  const int bm = blockIdx.x;   // 0..1
  const int bn = blockIdx.y;   // 0..7
  const int tid = threadIdx.x;
  const int wave = tid >> 6, lane = tid & 63;
  const int wm = (wave >> 1) * 64, wn = (wave & 1) * 64;
  const int r16 = lane & 15, kq = (lane >> 4) * 8;
  const ushort* Pbb = Pb + (size_t)b * KN * KN;
  const ushort* hbb = hb + (size_t)b * KN * DD;
  f32x4 acc[4][4] = {};

  for (int jt = 0; jt < KN; jt += BK) {
    // A: Pbar rows (i-major, j contiguous). 512 chunks of 8, 2/thread.
    for (int it = 0; it < 2; ++it) {
      int c = tid + 256 * it;
      int row = c >> 2, kp = (c & 3) * 8;
      short8 v = *reinterpret_cast<const short8*>(&Pbb[(size_t)(bm * BM + row) * KN + jt + kp]);
      *reinterpret_cast<short8*>(&As[row][kp]) = v;
    }
    // B: h[b][j][d], need Bs[d][j] (transpose in staging). 2 chunks of 8/thread.
    for (int it = 0; it < 2; ++it) {
      int c = tid + 256 * it;
      int jr = c >> 4, dp = (c & 15) * 8;
      short8 v = *reinterpret_cast<const short8*>(&hbb[(size_t)(jt + jr) * DD + bn * BN + dp]);
      for (int e = 0; e < 8; ++e) Bs[dp + e][jr] = (ushort)(short)v[e];
    }
    __syncthreads();
    short8 af[4], bf[4];
    for (int mf = 0; mf < 4; ++mf)
      af[mf] = *reinterpret_cast<const short8*>(&As[wm + mf * 16 + r16][kq]);
    for (int nf = 0; nf < 4; ++nf)
      bf[nf] = *reinterpret_cast<const short8*>(&Bs[wn + nf * 16 + r16][kq]);
    for (int mf = 0; mf < 4; ++mf)
      for (int nf = 0; nf < 4; ++nf)
        acc[mf][nf] = __builtin_amdgcn_mfma_f32_16x16x32_bf16(af[mf], bf[nf], acc[mf][nf], 0, 0, 0);
    __syncthreads();
  }
  for (int mf = 0; mf < 4; ++mf)
    for (int nf = 0; nf < 4; ++nf) {
      int col = bn * BN + wn + nf * 16 + r16;
      int rowb = bm * BM + wm + mf * 16 + (lane >> 4) * 4;
      for (int r = 0; r < 4; ++r) {
        size_t gi = ((size_t)b * KN + rowb + r) * DD + col;
        ypre[gi] = f2b(acc[mf][nf][r] + x[gi]);
      }
    }
}

// ---------------- K5: LayerNorm(ypre) -> out f32
__global__ __launch_bounds__(256) void k_ln(const ushort* __restrict__ ypre,
                                            const float* __restrict__ gamma,
                                            const float* __restrict__ beta,
                                            float* __restrict__ out) {
  __shared__ float redS[4], redQ[4];
  int tid = threadIdx.x;
  size_t row = blockIdx.x;
  ushort4 v = *reinterpret_cast<const ushort4*>(&ypre[row * DD + tid * 4]);
  float y0 = b2f(v.x), y1 = b2f(v.y), y2 = b2f(v.z), y3 = b2f(v.w);
  float s = y0 + y1 + y2 + y3;
  float q = y0 * y0 + y1 * y1 + y2 * y2 + y3 * y3;
  for (int off = 32; off; off >>= 1) {
    s += __shfl_down(s, off);
    q += __shfl_down(q, off);
  }
  int wave = tid >> 6, lane = tid & 63;
  if (lane == 0) { redS[wave] = s; redQ[wave] = q; }
  __syncthreads();
  float S = redS[0] + redS[1] + redS[2] + redS[3];
  float Q = redQ[0] + redQ[1] + redQ[2] + redQ[3];
  float mu = S * (1.0f / DD);
  float var = Q * (1.0f / DD) - mu * mu;
  float inv = rsqrtf(var + 1e-5f);
  float4 g = *reinterpret_cast<const float4*>(&gamma[tid * 4]);
  float4 bt = *reinterpret_cast<const float4*>(&beta[tid * 4]);
  float4 o;
  o.x = (y0 - mu) * inv * g.x + bt.x;
  o.y = (y1 - mu) * inv * g.y + bt.y;
  o.z = (y2 - mu) * inv * g.z + bt.z;
  o.w = (y3 - mu) * inv * g.w + bt.w;
  *reinterpret_cast<float4*>(&out[row * DD + tid * 4]) = o;
}

extern "C" void kernel_launch(void* const* d_in, const int* in_sizes, int n_in,
                              void* d_out, int out_size, void* d_ws, size_t ws_size,
                              hipStream_t stream) {
  const float* x     = (const float*)d_in[0];
  const int*   adj   = (const int*)d_in[1];
  const float* W     = (const float*)d_in[2];
  const float* a     = (const float*)d_in[3];
  const float* gamma = (const float*)d_in[4];
  const float* beta  = (const float*)d_in[5];
  float* out = (float*)d_out;

  char* ws = (char*)d_ws;
  const size_t OFS_WT   = 0;                       // 2 MB
  const size_t OFS_HB   = 2097152;                 // 33.5 MB
  const size_t OFS_FI   = 35651584;                // 128 KB
  const size_t OFS_FJ   = 35782656;                // 128 KB
  const size_t OFS_PB   = 35913728;                // 8.4 MB
  const size_t OFS_YP   = 44302336;                // 33.5 MB
  const size_t NEED     = 77856768;
  if (ws_size < NEED) return;  // workspace too small; bail (will fail validation loudly)

  ushort* WTb = (ushort*)(ws + OFS_WT);
  ushort* hb  = (ushort*)(ws + OFS_HB);
  float*  fi  = (float*)(ws + OFS_FI);
  float*  fj  = (float*)(ws + OFS_FJ);
  ushort* Pb  = (ushort*)(ws + OFS_PB);
  ushort* yp  = (ushort*)(ws + OFS_YP);

  k_wT<<<dim3(32, 32), dim3(32, 8), 0, stream>>>(W, WTb);
  k_gemm_h<<<dim3(128, 8), 256, 0, stream>>>(x, WTb, hb);
  k_f<<<4096, 256, 0, stream>>>(hb, a, fi, fj);
  k_attn<<<dim3(256, 64), 256, 0, stream>>>(fi, fj, adj, Pb);
  k_gemm_o<<<dim3(2, 8, 64), 256, 0, stream>>>(Pb, hb, x, yp);
  k_ln<<<16384, 256, 0, stream>>>(yp, gamma, beta, out);
}

// Round 2
// 186.646 us; speedup vs baseline: 1.0279x; 1.0279x over previous
//
#include <hip/hip_runtime.h>
#include <hip/hip_bf16.h>

#define KN 256
#define DD 1024
#define HH 2

typedef __attribute__((ext_vector_type(8))) short short8;
typedef __attribute__((ext_vector_type(4))) float f32x4;

__device__ __forceinline__ ushort f2b(float f) {
  union { float f; unsigned u; } v; v.f = f;
  unsigned u = v.u;
  return (ushort)((u + 0x7fffu + ((u >> 16) & 1u)) >> 16);
}
__device__ __forceinline__ float b2f(ushort h) {
  union { unsigned u; float f; } v; v.u = ((unsigned)h) << 16;
  return v.f;
}
__device__ __forceinline__ void gload16(const ushort* g, ushort* l) {
  __builtin_amdgcn_global_load_lds(
      (const __attribute__((address_space(1))) void*)g,
      (__attribute__((address_space(3))) void*)l, 16, 0, 0);
}

// ---------------- K-conv: x f32 -> xb bf16 (16.8M elems)
__global__ __launch_bounds__(256) void k_conv(const float* __restrict__ x,
                                              ushort* __restrict__ xb) {
  int c0 = blockIdx.x * 256 + threadIdx.x;
  for (int it = 0; it < 4; ++it) {
    size_t i = ((size_t)c0 + (size_t)it * 524288) * 8;
    float4 v0 = *reinterpret_cast<const float4*>(&x[i]);
    float4 v1 = *reinterpret_cast<const float4*>(&x[i + 4]);
    short8 o;
    o[0] = (short)f2b(v0.x); o[1] = (short)f2b(v0.y);
    o[2] = (short)f2b(v0.z); o[3] = (short)f2b(v0.w);
    o[4] = (short)f2b(v1.x); o[5] = (short)f2b(v1.y);
    o[6] = (short)f2b(v1.z); o[7] = (short)f2b(v1.w);
    *reinterpret_cast<short8*>(&xb[i]) = o;
  }
}

// ---------------- K0: W (DxD f32) -> WTb (DxD bf16, transposed)
__global__ __launch_bounds__(256) void k_wT(const float* __restrict__ W, ushort* __restrict__ WTb) {
  __shared__ float t[32][33];
  int tx = threadIdx.x, ty = threadIdx.y;
  int x = blockIdx.x * 32 + tx;
  int y0 = blockIdx.y * 32 + ty;
  for (int i = 0; i < 32; i += 8)
    t[ty + i][tx] = W[(size_t)(y0 + i) * DD + x];
  __syncthreads();
  int xo = blockIdx.y * 32 + tx;
  int yo = blockIdx.x * 32 + ty;
  for (int i = 0; i < 32; i += 8)
    WTb[(size_t)(yo + i) * DD + xo] = f2b(t[tx][ty + i]);
}

// ---------------- K1: h = xb @ W (M=16384, N=1024, K=1024), m97-style, gload_lds
__global__ __launch_bounds__(256) void k_gemm_h(const ushort* __restrict__ xb,
                                                const ushort* __restrict__ WTb,
                                                ushort* __restrict__ hb) {
  __shared__ ushort As[128 * 32];
  __shared__ ushort Bs[128 * 32];
  const int tid = threadIdx.x;
  const int bm = blockIdx.x;   // 0..127
  const int bn = blockIdx.y;   // 0..7
  const int w = tid >> 6, lane = tid & 63;
  const int wm = (w >> 1) * 64, wn = (w & 1) * 64;
  const int r16 = lane & 15, kq = (lane >> 4) * 8;
  const int srow = tid >> 2;          // 0..63
  const int scol = (tid & 3) * 8;
  const ushort* gA = xb + (size_t)(bm * 128 + srow) * DD + scol;
  const ushort* gB = WTb + (size_t)(bn * 128 + srow) * DD + scol;
  ushort* lA = &As[(w * 16) * 32];    // wave-uniform base, lane*16B auto
  ushort* lB = &Bs[(w * 16) * 32];
  f32x4 acc[4][4] = {};

  for (int kt = 0; kt < DD; kt += 32) {
    gload16(gA + kt, lA);
    gload16(gA + kt + (size_t)64 * DD, lA + 64 * 32);
    gload16(gB + kt, lB);
    gload16(gB + kt + (size_t)64 * DD, lB + 64 * 32);
    __syncthreads();
    short8 af[4], bf[4];
    for (int mf = 0; mf < 4; ++mf)
      af[mf] = *reinterpret_cast<const short8*>(&As[(wm + mf * 16 + r16) * 32 + kq]);
    for (int nf = 0; nf < 4; ++nf)
      bf[nf] = *reinterpret_cast<const short8*>(&Bs[(wn + nf * 16 + r16) * 32 + kq]);
    for (int mf = 0; mf < 4; ++mf)
      for (int nf = 0; nf < 4; ++nf)
        acc[mf][nf] = __builtin_amdgcn_mfma_f32_16x16x32_bf16(af[mf], bf[nf], acc[mf][nf], 0, 0, 0);
    __syncthreads();
  }
  for (int mf = 0; mf < 4; ++mf)
    for (int nf = 0; nf < 4; ++nf) {
      int col = bn * 128 + wn + nf * 16 + r16;
      int rowb = bm * 128 + wm + mf * 16 + (lane >> 4) * 4;
      for (int r = 0; r < 4; ++r)
        hb[(size_t)(rowb + r) * DD + col] = f2b(acc[mf][nf][r]);
    }
}

// ---------------- K2: f_i / f_j wave-dots (vectorized a loads)
__global__ __launch_bounds__(256) void k_f(const ushort* __restrict__ hb,
                                           const float* __restrict__ a,
                                           float* __restrict__ fi, float* __restrict__ fj) {
  int w = threadIdx.x >> 6, l = threadIdx.x & 63;
  size_t row = (size_t)blockIdx.x * 4 + w;
  const ushort* hr = hb + row * DD + l * 16;
  short8 v0 = *reinterpret_cast<const short8*>(hr);
  short8 v1 = *reinterpret_cast<const short8*>(hr + 8);
  float hv[16];
  for (int e = 0; e < 8; ++e) { hv[e] = b2f((ushort)v0[e]); hv[8 + e] = b2f((ushort)v1[e]); }
  float acc[4];
  for (int vec = 0; vec < 4; ++vec) {
    const float* av = a + vec * DD + l * 16;
    float s = 0.f;
    for (int q = 0; q < 4; ++q) {
      float4 av4 = *reinterpret_cast<const float4*>(&av[q * 4]);
      s += hv[q * 4 + 0] * av4.x + hv[q * 4 + 1] * av4.y +
           hv[q * 4 + 2] * av4.z + hv[q * 4 + 3] * av4.w;
    }
    acc[vec] = s;
  }
  for (int off = 32; off; off >>= 1)
    for (int vec = 0; vec < 4; ++vec) acc[vec] += __shfl_down(acc[vec], off);
  if (l == 0) {
    int b = (int)(row / KN), k = (int)(row % KN);
    fi[(b * HH + 0) * KN + k] = acc[0];  // a[:,0:D]   head0
    fj[(b * HH + 0) * KN + k] = acc[1];  // a[:,D:2D]  head0
    fi[(b * HH + 1) * KN + k] = acc[2];  // head1 src
    fj[(b * HH + 1) * KN + k] = acc[3];  // head1 dst
  }
}

// ---------------- K-hT: hb[b][j][d] -> hT[b][d][j]
__global__ __launch_bounds__(256) void k_hT(const ushort* __restrict__ hb,
                                            ushort* __restrict__ hT) {
  __shared__ ushort T[64][68];
  int b = blockIdx.z, bj = blockIdx.x, bd = blockIdx.y;
  int tid = threadIdx.x;
  const ushort* src = hb + ((size_t)b * KN + bj * 64) * DD + bd * 64;
  for (int i = 0; i < 4; ++i) {
    int idx = tid + 256 * i;
    int jr = idx >> 4, c4 = (idx & 15) * 4;
    *reinterpret_cast<ushort4*>(&T[jr][c4]) =
        *reinterpret_cast<const ushort4*>(&src[(size_t)jr * DD + c4]);
  }
  __syncthreads();
  ushort* dst = hT + ((size_t)b * DD + bd * 64) * KN + bj * 64;
  for (int i = 0; i < 4; ++i) {
    int idx = tid + 256 * i;
    int dr = idx >> 4, j4 = (idx & 15) * 4;
    ushort4 o;
    o.x = T[j4 + 0][dr]; o.y = T[j4 + 1][dr];
    o.z = T[j4 + 2][dr]; o.w = T[j4 + 3][dr];
    *reinterpret_cast<ushort4*>(&dst[(size_t)dr * KN + j4]) = o;
  }
}

// ---------------- K3: masked leaky softmax, head-mean -> Pbar bf16
__global__ __launch_bounds__(256) void k_attn(const float* __restrict__ fi, const float* __restrict__ fj,
                                              const int* __restrict__ adj, ushort* __restrict__ Pb) {
  const float NEGINF = -__builtin_huge_valf();
  int i = blockIdx.x, b = blockIdx.y, j = threadIdx.x;
  bool msk = adj[i * KN + j] != 0;
  float e0 = fi[(b * HH + 0) * KN + i] + fj[(b * HH + 0) * KN + j];
  float e1 = fi[(b * HH + 1) * KN + i] + fj[(b * HH + 1) * KN + j];
  e0 = e0 >= 0.f ? e0 : 0.2f * e0;
  e1 = e1 >= 0.f ? e1 : 0.2f * e1;
  if (!msk) { e0 = NEGINF; e1 = NEGINF; }
  __shared__ float red0[4], red1[4];
  int wave = j >> 6, lane = j & 63;
  float m0 = e0, m1 = e1;
  for (int off = 32; off; off >>= 1) {
    m0 = fmaxf(m0, __shfl_down(m0, off));
    m1 = fmaxf(m1, __shfl_down(m1, off));
  }
  if (lane == 0) { red0[wave] = m0; red1[wave] = m1; }
  __syncthreads();
  m0 = fmaxf(fmaxf(red0[0], red0[1]), fmaxf(red0[2], red0[3]));
  m1 = fmaxf(fmaxf(red1[0], red1[1]), fmaxf(red1[2], red1[3]));
  float p0 = (m0 == NEGINF) ? 0.f : __expf(e0 - m0);
  float p1 = (m1 == NEGINF) ? 0.f : __expf(e1 - m1);
  __syncthreads();
  float s0 = p0, s1 = p1;
  for (int off = 32; off; off >>= 1) {
    s0 += __shfl_down(s0, off);
    s1 += __shfl_down(s1, off);
  }
  if (lane == 0) { red0[wave] = s0; red1[wave] = s1; }
  __syncthreads();
  s0 = red0[0] + red0[1] + red0[2] + red0[3];
  s1 = red1[0] + red1[1] + red1[2] + red1[3];
  float r0 = s0 > 0.f ? p0 / s0 : 0.f;
  float r1 = s1 > 0.f ? p1 / s1 : 0.f;
  Pb[((size_t)b * KN + i) * KN + j] = f2b(0.5f * (r0 + r1));
}

// ---------------- K4: out0[b] = Pbar[b] @ h[b] + x  -> yp bf16
__global__ __launch_bounds__(256) void k_gemm_o(const ushort* __restrict__ Pb,
                                                const ushort* __restrict__ hT,
                                                const float* __restrict__ x,
                                                ushort* __restrict__ yp) {
  __shared__ ushort As[128 * 32];
  __shared__ ushort Bs[128 * 32];
  const int b = blockIdx.z;
  const int bm = blockIdx.x;   // 0..1
  const int bn = blockIdx.y;   // 0..7
  const int tid = threadIdx.x;
  const int w = tid >> 6, lane = tid & 63;
  const int wm = (w >> 1) * 64, wn = (w & 1) * 64;
  const int r16 = lane & 15, kq = (lane >> 4) * 8;
  const int srow = tid >> 2;
  const int scol = (tid & 3) * 8;
  const ushort* gA = Pb + (size_t)b * KN * KN + (size_t)(bm * 128 + srow) * KN + scol;
  const ushort* gB = hT + (size_t)b * DD * KN + (size_t)(bn * 128 + srow) * KN + scol;
  ushort* lA = &As[(w * 16) * 32];
  ushort* lB = &Bs[(w * 16) * 32];
  f32x4 acc[4][4] = {};

  for (int kt = 0; kt < KN; kt += 32) {
    gload16(gA + kt, lA);
    gload16(gA + kt + 64 * KN, lA + 64 * 32);
    gload16(gB + kt, lB);
    gload16(gB + kt + 64 * KN, lB + 64 * 32);
    __syncthreads();
    short8 af[4], bf[4];
    for (int mf = 0; mf < 4; ++mf)
      af[mf] = *reinterpret_cast<const short8*>(&As[(wm + mf * 16 + r16) * 32 + kq]);
    for (int nf = 0; nf < 4; ++nf)
      bf[nf] = *reinterpret_cast<const short8*>(&Bs[(wn + nf * 16 + r16) * 32 + kq]);
    for (int mf = 0; mf < 4; ++mf)
      for (int nf = 0; nf < 4; ++nf)
        acc[mf][nf] = __builtin_amdgcn_mfma_f32_16x16x32_bf16(af[mf], bf[nf], acc[mf][nf], 0, 0, 0);
    __syncthreads();
  }
  for (int mf = 0; mf < 4; ++mf)
    for (int nf = 0; nf < 4; ++nf) {
      int col = bn * 128 + wn + nf * 16 + r16;
      int rowb = bm * 128 + wm + mf * 16 + (lane >> 4) * 4;
      for (int r = 0; r < 4; ++r) {
        size_t gi = ((size_t)b * KN + rowb + r) * DD + col;
        yp[gi] = f2b(acc[mf][nf][r] + x[gi]);
      }
    }
}

// ---------------- K5: LayerNorm(yp bf16) -> out f32
__global__ __launch_bounds__(256) void k_ln(const ushort* __restrict__ yp,
                                            const float* __restrict__ gamma,
                                            const float* __restrict__ beta,
                                            float* __restrict__ out) {
  __shared__ float redS[4], redQ[4];
  int tid = threadIdx.x;
  size_t row = blockIdx.x;
  ushort4 v = *reinterpret_cast<const ushort4*>(&yp[row * DD + tid * 4]);
  float y0 = b2f(v.x), y1 = b2f(v.y), y2 = b2f(v.z), y3 = b2f(v.w);
  float s = y0 + y1 + y2 + y3;
  float q = y0 * y0 + y1 * y1 + y2 * y2 + y3 * y3;
  for (int off = 32; off; off >>= 1) {
    s += __shfl_down(s, off);
    q += __shfl_down(q, off);
  }
  int wave = tid >> 6, lane = tid & 63;
  if (lane == 0) { redS[wave] = s; redQ[wave] = q; }
  __syncthreads();
  float S = redS[0] + redS[1] + redS[2] + redS[3];
  float Q = redQ[0] + redQ[1] + redQ[2] + redQ[3];
  float mu = S * (1.0f / DD);
  float var = Q * (1.0f / DD) - mu * mu;
  float inv = rsqrtf(var + 1e-5f);
  float4 g = *reinterpret_cast<const float4*>(&gamma[tid * 4]);
  float4 bt = *reinterpret_cast<const float4*>(&beta[tid * 4]);
  float4 o;
  o.x = (y0 - mu) * inv * g.x + bt.x;
  o.y = (y1 - mu) * inv * g.y + bt.y;
  o.z = (y2 - mu) * inv * g.z + bt.z;
  o.w = (y3 - mu) * inv * g.w + bt.w;
  *reinterpret_cast<float4*>(&out[row * DD + tid * 4]) = o;
}

extern "C" void kernel_launch(void* const* d_in, const int* in_sizes, int n_in,
                              void* d_out, int out_size, void* d_ws, size_t ws_size,
                              hipStream_t stream) {
  const float* x     = (const float*)d_in[0];
  const int*   adj   = (const int*)d_in[1];
  const float* W     = (const float*)d_in[2];
  const float* a     = (const float*)d_in[3];
  const float* gamma = (const float*)d_in[4];
  const float* beta  = (const float*)d_in[5];
  float* out = (float*)d_out;

  char* ws = (char*)d_ws;
  // Overlaid layout (max live <= 77.86 MB, proven fits):
  //   [0, 2M)            WTb                      (wT -> gemm_h)
  //   [2M, 35.5M)        xb, then hT (k_hT on)    (conv -> gemm_h; hT -> gemm_o)
  //   [35.5M, 69M)       hb, then yp (gemm_o on)  (gemm_h -> k_f,k_hT; yp -> ln)
  //   [69M, 69.26M)      fi, fj
  //   [69.26M, 77.65M)   Pb
  const size_t OFS_WT = 0;
  const size_t OFS_XB = 2097152;
  const size_t OFS_HB = 35651584;
  const size_t OFS_FI = 69206016;
  const size_t OFS_FJ = 69337088;
  const size_t OFS_PB = 69468160;
  const size_t NEED   = 77856768;
  if (ws_size < NEED) return;

  ushort* WTb = (ushort*)(ws + OFS_WT);
  ushort* xb  = (ushort*)(ws + OFS_XB);
  ushort* hT  = (ushort*)(ws + OFS_XB);   // aliases xb (xb dead after gemm_h)
  ushort* hb  = (ushort*)(ws + OFS_HB);
  ushort* yp  = (ushort*)(ws + OFS_HB);   // aliases hb (hb dead after k_hT)
  float*  fi  = (float*)(ws + OFS_FI);
  float*  fj  = (float*)(ws + OFS_FJ);
  ushort* Pb  = (ushort*)(ws + OFS_PB);

  k_conv<<<2048, 256, 0, stream>>>(x, xb);
  k_wT<<<dim3(32, 32), dim3(32, 8), 0, stream>>>(W, WTb);
  k_gemm_h<<<dim3(128, 8), 256, 0, stream>>>(xb, WTb, hb);
  k_f<<<4096, 256, 0, stream>>>(hb, a, fi, fj);
  k_hT<<<dim3(4, 16, 64), 256, 0, stream>>>(hb, hT);
  k_attn<<<dim3(256, 64), 256, 0, stream>>>(fi, fj, adj, Pb);
  k_gemm_o<<<dim3(2, 8, 64), 256, 0, stream>>>(Pb, hT, x, yp);
  k_ln<<<16384, 256, 0, stream>>>(yp, gamma, beta, out);
}

// Round 3
// 185.889 us; speedup vs baseline: 1.0321x; 1.0041x over previous
//
#include <hip/hip_runtime.h>
#include <hip/hip_bf16.h>

#define KN 256
#define DD 1024
#define HH 2

typedef __attribute__((ext_vector_type(8))) short short8;
typedef __attribute__((ext_vector_type(4))) float f32x4;

__device__ __forceinline__ ushort f2b(float f) {
  union { float f; unsigned u; } v; v.f = f;
  unsigned u = v.u;
  return (ushort)((u + 0x7fffu + ((u >> 16) & 1u)) >> 16);
}
__device__ __forceinline__ float b2f(ushort h) {
  union { unsigned u; float f; } v; v.u = ((unsigned)h) << 16;
  return v.f;
}
__device__ __forceinline__ void gload16(const ushort* g, ushort* l) {
  __builtin_amdgcn_global_load_lds(
      (const __attribute__((address_space(1))) void*)g,
      (__attribute__((address_space(3))) void*)l, 16, 0, 0);
}

// ---------------- K-conv: x f32 -> xb bf16
__global__ __launch_bounds__(256) void k_conv(const float* __restrict__ x,
                                              ushort* __restrict__ xb) {
  int c0 = blockIdx.x * 256 + threadIdx.x;
  for (int it = 0; it < 4; ++it) {
    size_t i = ((size_t)c0 + (size_t)it * 524288) * 8;
    float4 v0 = *reinterpret_cast<const float4*>(&x[i]);
    float4 v1 = *reinterpret_cast<const float4*>(&x[i + 4]);
    short8 o;
    o[0] = (short)f2b(v0.x); o[1] = (short)f2b(v0.y);
    o[2] = (short)f2b(v0.z); o[3] = (short)f2b(v0.w);
    o[4] = (short)f2b(v1.x); o[5] = (short)f2b(v1.y);
    o[6] = (short)f2b(v1.z); o[7] = (short)f2b(v1.w);
    *reinterpret_cast<short8*>(&xb[i]) = o;
  }
}

// ---------------- K0: W (DxD f32) -> WTb (DxD bf16, transposed)
__global__ __launch_bounds__(256) void k_wT(const float* __restrict__ W, ushort* __restrict__ WTb) {
  __shared__ float t[32][33];
  int tx = threadIdx.x, ty = threadIdx.y;
  int x = blockIdx.x * 32 + tx;
  int y0 = blockIdx.y * 32 + ty;
  for (int i = 0; i < 32; i += 8)
    t[ty + i][tx] = W[(size_t)(y0 + i) * DD + x];
  __syncthreads();
  int xo = blockIdx.y * 32 + tx;
  int yo = blockIdx.x * 32 + ty;
  for (int i = 0; i < 32; i += 8)
    WTb[(size_t)(yo + i) * DD + xo] = f2b(t[tx][ty + i]);
}

// ---------------- K1: h = xb @ W, 128x128 tile, 2-phase dbuf + kq-swizzle
__device__ __forceinline__ void gh_stage(const ushort* gA0, const ushort* gB0, int kt,
                                         ushort* As, ushort* Bs, int tid) {
  int wb = tid & ~63;
  for (int it = 0; it < 2; ++it) {
    int slot = it * 256 + tid;
    int row = slot >> 2, kc = slot & 3;
    int kcs = kc ^ (((row >> 1) & 1) << 1);
    gload16(gA0 + (size_t)row * DD + kt + kcs * 8, As + (size_t)(it * 256 + wb) * 8);
    gload16(gB0 + (size_t)row * DD + kt + kcs * 8, Bs + (size_t)(it * 256 + wb) * 8);
  }
}

__global__ __launch_bounds__(256) void k_gemm_h(const ushort* __restrict__ xb,
                                                const ushort* __restrict__ WTb,
                                                ushort* __restrict__ hb) {
  __shared__ ushort As[2][4096];
  __shared__ ushort Bs[2][4096];
  const int tid = threadIdx.x;
  const int bm = blockIdx.x;   // 0..127
  const int bn = blockIdx.y;   // 0..7
  const int w = tid >> 6, lane = tid & 63;
  const int wm = (w >> 1) * 64, wn = (w & 1) * 64;
  const int r16 = lane & 15, kqi = lane >> 4;
  const ushort* gA0 = xb + (size_t)(bm * 128) * DD;
  const ushort* gB0 = WTb + (size_t)(bn * 128) * DD;
  f32x4 acc[4][4] = {};

  gh_stage(gA0, gB0, 0, As[0], Bs[0], tid);
  __syncthreads();
  for (int kt = 0; kt < DD; kt += 32) {
    int cur = (kt >> 5) & 1;
    if (kt + 32 < DD)
      gh_stage(gA0, gB0, kt + 32, As[cur ^ 1], Bs[cur ^ 1], tid);
    const ushort* Ac = As[cur];
    const ushort* Bc = Bs[cur];
    short8 af[4], bf[4];
    for (int mf = 0; mf < 4; ++mf) {
      int row = wm + mf * 16 + r16;
      af[mf] = *reinterpret_cast<const short8*>(Ac + row * 32 + (kqi ^ (((row >> 1) & 1) << 1)) * 8);
    }
    for (int nf = 0; nf < 4; ++nf) {
      int row = wn + nf * 16 + r16;
      bf[nf] = *reinterpret_cast<const short8*>(Bc + row * 32 + (kqi ^ (((row >> 1) & 1) << 1)) * 8);
    }
    for (int mf = 0; mf < 4; ++mf)
      for (int nf = 0; nf < 4; ++nf)
        acc[mf][nf] = __builtin_amdgcn_mfma_f32_16x16x32_bf16(af[mf], bf[nf], acc[mf][nf], 0, 0, 0);
    __syncthreads();
  }
  for (int mf = 0; mf < 4; ++mf)
    for (int nf = 0; nf < 4; ++nf) {
      int col = bn * 128 + wn + nf * 16 + r16;
      int rowb = bm * 128 + wm + mf * 16 + (lane >> 4) * 4;
      for (int r = 0; r < 4; ++r)
        hb[(size_t)(rowb + r) * DD + col] = f2b(acc[mf][nf][r]);
    }
}

// ---------------- K2: f_i / f_j wave-dots
__global__ __launch_bounds__(256) void k_f(const ushort* __restrict__ hb,
                                           const float* __restrict__ a,
                                           float* __restrict__ fi, float* __restrict__ fj) {
  int w = threadIdx.x >> 6, l = threadIdx.x & 63;
  size_t row = (size_t)blockIdx.x * 4 + w;
  const ushort* hr = hb + row * DD + l * 16;
  short8 v0 = *reinterpret_cast<const short8*>(hr);
  short8 v1 = *reinterpret_cast<const short8*>(hr + 8);
  float hv[16];
  for (int e = 0; e < 8; ++e) { hv[e] = b2f((ushort)v0[e]); hv[8 + e] = b2f((ushort)v1[e]); }
  float acc[4];
  for (int vec = 0; vec < 4; ++vec) {
    const float* av = a + vec * DD + l * 16;
    float s = 0.f;
    for (int q = 0; q < 4; ++q) {
      float4 av4 = *reinterpret_cast<const float4*>(&av[q * 4]);
      s += hv[q * 4 + 0] * av4.x + hv[q * 4 + 1] * av4.y +
           hv[q * 4 + 2] * av4.z + hv[q * 4 + 3] * av4.w;
    }
    acc[vec] = s;
  }
  for (int off = 32; off; off >>= 1)
    for (int vec = 0; vec < 4; ++vec) acc[vec] += __shfl_down(acc[vec], off);
  if (l == 0) {
    int b = (int)(row / KN), k = (int)(row % KN);
    fi[(b * HH + 0) * KN + k] = acc[0];
    fj[(b * HH + 0) * KN + k] = acc[1];
    fi[(b * HH + 1) * KN + k] = acc[2];
    fj[(b * HH + 1) * KN + k] = acc[3];
  }
}

// ---------------- K-hT: hb[b][j][d] -> hT[b][d][j]
__global__ __launch_bounds__(256) void k_hT(const ushort* __restrict__ hb,
                                            ushort* __restrict__ hT) {
  __shared__ ushort T[64][68];
  int b = blockIdx.z, bj = blockIdx.x, bd = blockIdx.y;
  int tid = threadIdx.x;
  const ushort* src = hb + ((size_t)b * KN + bj * 64) * DD + bd * 64;
  for (int i = 0; i < 4; ++i) {
    int idx = tid + 256 * i;
    int jr = idx >> 4, c4 = (idx & 15) * 4;
    *reinterpret_cast<ushort4*>(&T[jr][c4]) =
        *reinterpret_cast<const ushort4*>(&src[(size_t)jr * DD + c4]);
  }
  __syncthreads();
  ushort* dst = hT + ((size_t)b * DD + bd * 64) * KN + bj * 64;
  for (int i = 0; i < 4; ++i) {
    int idx = tid + 256 * i;
    int dr = idx >> 4, j4 = (idx & 15) * 4;
    ushort4 o;
    o.x = T[j4 + 0][dr]; o.y = T[j4 + 1][dr];
    o.z = T[j4 + 2][dr]; o.w = T[j4 + 3][dr];
    *reinterpret_cast<ushort4*>(&dst[(size_t)dr * KN + j4]) = o;
  }
}

// ---------------- K3: masked leaky softmax, head-mean -> Pbar bf16 (wave per row)
__global__ __launch_bounds__(256) void k_attn(const float* __restrict__ fi, const float* __restrict__ fj,
                                              const int* __restrict__ adj, ushort* __restrict__ Pb) {
  int w = threadIdx.x >> 6, l = threadIdx.x & 63;
  int gw = blockIdx.x * 4 + w;
  int b = gw >> 8, i = gw & 255;
  int4 am = *reinterpret_cast<const int4*>(adj + i * KN + l * 4);
  int msk[4] = { am.x, am.y, am.z, am.w };
  float fi0 = fi[(b * HH + 0) * KN + i];
  float fi1 = fi[(b * HH + 1) * KN + i];
  float4 fj0 = *reinterpret_cast<const float4*>(fj + (b * HH + 0) * KN + l * 4);
  float4 fj1 = *reinterpret_cast<const float4*>(fj + (b * HH + 1) * KN + l * 4);
  float e0[4] = { fi0 + fj0.x, fi0 + fj0.y, fi0 + fj0.z, fi0 + fj0.w };
  float e1[4] = { fi1 + fj1.x, fi1 + fj1.y, fi1 + fj1.z, fi1 + fj1.w };
  const float NEGINF = -3.0e38f;
  float m0 = NEGINF, m1 = NEGINF;
  for (int e = 0; e < 4; ++e) {
    e0[e] = e0[e] >= 0.f ? e0[e] : 0.2f * e0[e];
    e1[e] = e1[e] >= 0.f ? e1[e] : 0.2f * e1[e];
    if (msk[e]) { m0 = fmaxf(m0, e0[e]); m1 = fmaxf(m1, e1[e]); }
  }
  for (int off = 1; off < 64; off <<= 1) {
    m0 = fmaxf(m0, __shfl_xor(m0, off));
    m1 = fmaxf(m1, __shfl_xor(m1, off));
  }
  float p0[4], p1[4], s0 = 0.f, s1 = 0.f;
  for (int e = 0; e < 4; ++e) {
    p0[e] = msk[e] ? __expf(e0[e] - m0) : 0.f;
    p1[e] = msk[e] ? __expf(e1[e] - m1) : 0.f;
    s0 += p0[e]; s1 += p1[e];
  }
  for (int off = 1; off < 64; off <<= 1) {
    s0 += __shfl_xor(s0, off);
    s1 += __shfl_xor(s1, off);
  }
  float i0 = s0 > 0.f ? 1.f / s0 : 0.f;
  float i1 = s1 > 0.f ? 1.f / s1 : 0.f;
  ushort4 o;
  o.x = f2b(0.5f * (p0[0] * i0 + p1[0] * i1));
  o.y = f2b(0.5f * (p0[1] * i0 + p1[1] * i1));
  o.z = f2b(0.5f * (p0[2] * i0 + p1[2] * i1));
  o.w = f2b(0.5f * (p0[3] * i0 + p1[3] * i1));
  *reinterpret_cast<ushort4*>(&Pb[((size_t)b * KN + i) * KN + l * 4]) = o;
}

// ---------------- K4: out = LN(Pbar[b] @ h[b] + x) -- fused, full-D rows per block
__global__ __launch_bounds__(512) void k_gemm_o_ln(const ushort* __restrict__ Pb,
                                                   const ushort* __restrict__ hT,
                                                   const float* __restrict__ x,
                                                   const float* __restrict__ gamma,
                                                   const float* __restrict__ beta,
                                                   float* __restrict__ out) {
  __shared__ ushort As[32 * 32];
  __shared__ ushort Bs[1024 * 32];
  __shared__ float red[32][8][2];
  const int b = blockIdx.y;
  const int it32 = blockIdx.x;     // i-tile 0..7 (32 rows each)
  const int tid = threadIdx.x;
  const int w = tid >> 6, lane = tid & 63;
  const int r16 = lane & 15, kqi = lane >> 4, g = kqi;
  const ushort* Pbb = Pb + (size_t)b * KN * KN + (size_t)(it32 * 32) * KN;
  const ushort* hTb = hT + (size_t)b * DD * KN;
  f32x4 acc[2][8] = {};

  for (int jt = 0; jt < KN; jt += 32) {
    if (tid < 128) {
      int row = tid >> 2, kc = tid & 3;
      int kcs = kc ^ (((row >> 1) & 1) << 1);
      gload16(Pbb + (size_t)row * KN + jt + kcs * 8, As + (size_t)(tid & ~63) * 8);
    }
    for (int itb = 0; itb < 8; ++itb) {
      int slot = itb * 512 + tid;
      int row = slot >> 2, kc = slot & 3;
      int kcs = kc ^ (((row >> 1) & 1) << 1);
      gload16(hTb + (size_t)row * KN + jt + kcs * 8, Bs + (size_t)(itb * 512 + (tid & ~63)) * 8);
    }
    __syncthreads();
    short8 af[2];
    for (int mf = 0; mf < 2; ++mf) {
      int row = mf * 16 + r16;
      af[mf] = *reinterpret_cast<const short8*>(As + row * 32 + (kqi ^ (((row >> 1) & 1) << 1)) * 8);
    }
    for (int nf = 0; nf < 8; ++nf) {
      int row = w * 128 + nf * 16 + r16;
      short8 bf = *reinterpret_cast<const short8*>(Bs + (size_t)row * 32 + (kqi ^ (((row >> 1) & 1) << 1)) * 8);
      for (int mf = 0; mf < 2; ++mf)
        acc[mf][nf] = __builtin_amdgcn_mfma_f32_16x16x32_bf16(af[mf], bf, acc[mf][nf], 0, 0, 0);
    }
    __syncthreads();
  }

  // residual add + per-row partial sums
  float ps[2][4] = {}, qs[2][4] = {};
  #pragma unroll
  for (int mf = 0; mf < 2; ++mf)
    #pragma unroll
    for (int nf = 0; nf < 8; ++nf) {
      int col = w * 128 + nf * 16 + r16;
      #pragma unroll
      for (int rr = 0; rr < 4; ++rr) {
        int i = it32 * 32 + mf * 16 + g * 4 + rr;
        size_t gi = ((size_t)(b * KN + i)) * DD + col;
        float v = acc[mf][nf][rr] + x[gi];
        acc[mf][nf][rr] = v;
        ps[mf][rr] += v; qs[mf][rr] += v * v;
      }
    }
  #pragma unroll
  for (int off = 1; off < 16; off <<= 1)
    #pragma unroll
    for (int mf = 0; mf < 2; ++mf)
      #pragma unroll
      for (int rr = 0; rr < 4; ++rr) {
        ps[mf][rr] += __shfl_xor(ps[mf][rr], off);
        qs[mf][rr] += __shfl_xor(qs[mf][rr], off);
      }
  if (r16 == 0) {
    #pragma unroll
    for (int mf = 0; mf < 2; ++mf)
      #pragma unroll
      for (int rr = 0; rr < 4; ++rr) {
        red[mf * 16 + g * 4 + rr][w][0] = ps[mf][rr];
        red[mf * 16 + g * 4 + rr][w][1] = qs[mf][rr];
      }
  }
  __syncthreads();
  float mu[2][4], inv[2][4];
  #pragma unroll
  for (int mf = 0; mf < 2; ++mf)
    #pragma unroll
    for (int rr = 0; rr < 4; ++rr) {
      int il = mf * 16 + g * 4 + rr;
      float S = 0.f, Q = 0.f;
      #pragma unroll
      for (int wv = 0; wv < 8; ++wv) { S += red[il][wv][0]; Q += red[il][wv][1]; }
      float m = S * (1.0f / DD);
      float var = Q * (1.0f / DD) - m * m;
      mu[mf][rr] = m;
      inv[mf][rr] = rsqrtf(var + 1e-5f);
    }
  #pragma unroll
  for (int nf = 0; nf < 8; ++nf) {
    int col = w * 128 + nf * 16 + r16;
    float gm = gamma[col], bt = beta[col];
    #pragma unroll
    for (int mf = 0; mf < 2; ++mf)
      #pragma unroll
      for (int rr = 0; rr < 4; ++rr) {
        int i = it32 * 32 + mf * 16 + g * 4 + rr;
        size_t gi = ((size_t)(b * KN + i)) * DD + col;
        out[gi] = (acc[mf][nf][rr] - mu[mf][rr]) * inv[mf][rr] * gm + bt;
      }
  }
}

extern "C" void kernel_launch(void* const* d_in, const int* in_sizes, int n_in,
                              void* d_out, int out_size, void* d_ws, size_t ws_size,
                              hipStream_t stream) {
  const float* x     = (const float*)d_in[0];
  const int*   adj   = (const int*)d_in[1];
  const float* W     = (const float*)d_in[2];
  const float* a     = (const float*)d_in[3];
  const float* gamma = (const float*)d_in[4];
  const float* beta  = (const float*)d_in[5];
  float* out = (float*)d_out;

  char* ws = (char*)d_ws;
  const size_t OFS_WT = 0;
  const size_t OFS_XB = 2097152;    // xb, then hT (aliased)
  const size_t OFS_HB = 35651584;   // hb
  const size_t OFS_FI = 69206016;
  const size_t OFS_FJ = 69337088;
  const size_t OFS_PB = 69468160;
  const size_t NEED   = 77856768;
  if (ws_size < NEED) return;

  ushort* WTb = (ushort*)(ws + OFS_WT);
  ushort* xb  = (ushort*)(ws + OFS_XB);
  ushort* hT  = (ushort*)(ws + OFS_XB);   // aliases xb (xb dead after gemm_h)
  ushort* hb  = (ushort*)(ws + OFS_HB);
  float*  fi  = (float*)(ws + OFS_FI);
  float*  fj  = (float*)(ws + OFS_FJ);
  ushort* Pb  = (ushort*)(ws + OFS_PB);

  k_conv<<<2048, 256, 0, stream>>>(x, xb);
  k_wT<<<dim3(32, 32), dim3(32, 8), 0, stream>>>(W, WTb);
  k_gemm_h<<<dim3(128, 8), 256, 0, stream>>>(xb, WTb, hb);
  k_f<<<4096, 256, 0, stream>>>(hb, a, fi, fj);
  k_hT<<<dim3(4, 16, 64), 256, 0, stream>>>(hb, hT);
  k_attn<<<4096, 256, 0, stream>>>(fi, fj, adj, Pb);
  k_gemm_o_ln<<<dim3(8, 64), 512, 0, stream>>>(Pb, hT, x, gamma, beta, out);
}

// Round 4
// 143.785 us; speedup vs baseline: 1.3343x; 1.2928x over previous
//
#include <hip/hip_runtime.h>
#include <hip/hip_bf16.h>

#define KN 256
#define DD 1024
#define HH 2

typedef __attribute__((ext_vector_type(8))) short short8;
typedef __attribute__((ext_vector_type(4))) float f32x4;

__device__ __forceinline__ ushort f2b(float f) {
  union { float f; unsigned u; } v; v.f = f;
  unsigned u = v.u;
  return (ushort)((u + 0x7fffu + ((u >> 16) & 1u)) >> 16);
}
__device__ __forceinline__ float b2f(ushort h) {
  union { unsigned u; float f; } v; v.u = ((unsigned)h) << 16;
  return v.f;
}
__device__ __forceinline__ void gload16(const ushort* g, ushort* l) {
  __builtin_amdgcn_global_load_lds(
      (const __attribute__((address_space(1))) void*)g,
      (__attribute__((address_space(3))) void*)l, 16, 0, 0);
}

// ---------------- K-conv: x f32 -> xb bf16
__global__ __launch_bounds__(256) void k_conv(const float* __restrict__ x,
                                              ushort* __restrict__ xb) {
  int c0 = blockIdx.x * 256 + threadIdx.x;
  for (int it = 0; it < 4; ++it) {
    size_t i = ((size_t)c0 + (size_t)it * 524288) * 8;
    float4 v0 = *reinterpret_cast<const float4*>(&x[i]);
    float4 v1 = *reinterpret_cast<const float4*>(&x[i + 4]);
    short8 o;
    o[0] = (short)f2b(v0.x); o[1] = (short)f2b(v0.y);
    o[2] = (short)f2b(v0.z); o[3] = (short)f2b(v0.w);
    o[4] = (short)f2b(v1.x); o[5] = (short)f2b(v1.y);
    o[6] = (short)f2b(v1.z); o[7] = (short)f2b(v1.w);
    *reinterpret_cast<short8*>(&xb[i]) = o;
  }
}

// ---------------- K0: W (DxD f32) -> WTb (DxD bf16, transposed)
__global__ __launch_bounds__(256) void k_wT(const float* __restrict__ W, ushort* __restrict__ WTb) {
  __shared__ float t[32][33];
  int tx = threadIdx.x, ty = threadIdx.y;
  int x = blockIdx.x * 32 + tx;
  int y0 = blockIdx.y * 32 + ty;
  for (int i = 0; i < 32; i += 8)
    t[ty + i][tx] = W[(size_t)(y0 + i) * DD + x];
  __syncthreads();
  int xo = blockIdx.y * 32 + tx;
  int yo = blockIdx.x * 32 + ty;
  for (int i = 0; i < 32; i += 8)
    WTb[(size_t)(yo + i) * DD + xo] = f2b(t[tx][ty + i]);
}

// ---------------- K1: h = xb @ W -> write TRANSPOSED hT[b][d][j]
__device__ __forceinline__ void gh_stage(const ushort* gA0, const ushort* gB0, int kt,
                                         ushort* As, ushort* Bs, int tid) {
  int wb = tid & ~63;
  for (int it = 0; it < 2; ++it) {
    int slot = it * 256 + tid;
    int row = slot >> 2, kc = slot & 3;
    int kcs = kc ^ (((row >> 1) & 1) << 1);
    gload16(gA0 + (size_t)row * DD + kt + kcs * 8, As + (size_t)(it * 256 + wb) * 8);
    gload16(gB0 + (size_t)row * DD + kt + kcs * 8, Bs + (size_t)(it * 256 + wb) * 8);
  }
}

__global__ __launch_bounds__(256) void k_gemm_h(const ushort* __restrict__ xb,
                                                const ushort* __restrict__ WTb,
                                                ushort* __restrict__ hT) {
  __shared__ ushort As[2][4096];
  __shared__ ushort Bs[2][4096];
  const int tid = threadIdx.x;
  const int bm = blockIdx.x;   // 0..127 (row tile, batch-half)
  const int bn = blockIdx.y;   // 0..7
  const int w = tid >> 6, lane = tid & 63;
  const int wm = (w >> 1) * 64, wn = (w & 1) * 64;
  const int r16 = lane & 15, kqi = lane >> 4;
  const ushort* gA0 = xb + (size_t)(bm * 128) * DD;
  const ushort* gB0 = WTb + (size_t)(bn * 128) * DD;
  f32x4 acc[4][4] = {};

  gh_stage(gA0, gB0, 0, As[0], Bs[0], tid);
  __syncthreads();
  for (int kt = 0; kt < DD; kt += 32) {
    int cur = (kt >> 5) & 1;
    if (kt + 32 < DD)
      gh_stage(gA0, gB0, kt + 32, As[cur ^ 1], Bs[cur ^ 1], tid);
    const ushort* Ac = As[cur];
    const ushort* Bc = Bs[cur];
    short8 af[4], bf[4];
    for (int mf = 0; mf < 4; ++mf) {
      int row = wm + mf * 16 + r16;
      af[mf] = *reinterpret_cast<const short8*>(Ac + row * 32 + (kqi ^ (((row >> 1) & 1) << 1)) * 8);
    }
    for (int nf = 0; nf < 4; ++nf) {
      int row = wn + nf * 16 + r16;
      bf[nf] = *reinterpret_cast<const short8*>(Bc + row * 32 + (kqi ^ (((row >> 1) & 1) << 1)) * 8);
    }
    for (int mf = 0; mf < 4; ++mf)
      for (int nf = 0; nf < 4; ++nf)
        acc[mf][nf] = __builtin_amdgcn_mfma_f32_16x16x32_bf16(af[mf], bf[nf], acc[mf][nf], 0, 0, 0);
    __syncthreads();
  }
  // transposed epilogue: 4 acc regs = 4 consecutive j -> one 8B store
  const int b = bm >> 1;
  const int j0base = (bm & 1) * 128 + wm;
  for (int mf = 0; mf < 4; ++mf) {
    int j0 = j0base + mf * 16 + (lane >> 4) * 4;
    for (int nf = 0; nf < 4; ++nf) {
      int C = bn * 128 + wn + nf * 16 + r16;
      ushort4 o;
      o.x = f2b(acc[mf][nf][0]); o.y = f2b(acc[mf][nf][1]);
      o.z = f2b(acc[mf][nf][2]); o.w = f2b(acc[mf][nf][3]);
      *reinterpret_cast<ushort4*>(&hT[((size_t)b * DD + C) * KN + j0]) = o;
    }
  }
}

// ---------------- K2: f partials from hT (axpy form). block=(b, dq): 256 d-rows
__global__ __launch_bounds__(256) void k_f(const ushort* __restrict__ hT,
                                           const float* __restrict__ a,
                                           float* __restrict__ fip, float* __restrict__ fjp) {
  __shared__ float als[4][256];
  int b = blockIdx.x, dq = blockIdx.y;
  int tid = threadIdx.x;
  for (int v = 0; v < 4; ++v) als[v][tid] = a[v * DD + dq * 256 + tid];
  __syncthreads();
  const ushort* base = hT + ((size_t)b * DD + dq * 256) * KN + tid;
  float a0 = 0.f, a1 = 0.f, a2 = 0.f, a3 = 0.f;
  #pragma unroll 8
  for (int d = 0; d < 256; ++d) {
    float hv = b2f(base[(size_t)d * KN]);
    a0 += hv * als[0][d];
    a1 += hv * als[1][d];
    a2 += hv * als[2][d];
    a3 += hv * als[3][d];
  }
  size_t o = ((size_t)(dq * 64 + b) * HH) * KN + tid;
  fip[o] = a0;        // head0 src
  fjp[o] = a1;        // head0 dst
  fip[o + KN] = a2;   // head1 src
  fjp[o + KN] = a3;   // head1 dst
}

// ---------------- K3: masked leaky softmax, head-mean -> Pbar bf16 (wave per row)
__global__ __launch_bounds__(256) void k_attn(const float* __restrict__ fip, const float* __restrict__ fjp,
                                              const int* __restrict__ adj, ushort* __restrict__ Pb) {
  int w = threadIdx.x >> 6, l = threadIdx.x & 63;
  int gw = blockIdx.x * 4 + w;
  int b = gw >> 8, i = gw & 255;
  int4 am = *reinterpret_cast<const int4*>(adj + i * KN + l * 4);
  int msk[4] = { am.x, am.y, am.z, am.w };
  float fi0 = 0.f, fi1 = 0.f;
  float fj0[4] = {0.f, 0.f, 0.f, 0.f}, fj1[4] = {0.f, 0.f, 0.f, 0.f};
  for (int dq = 0; dq < 4; ++dq) {
    size_t o = ((size_t)(dq * 64 + b) * HH) * KN;
    fi0 += fip[o + i];
    fi1 += fip[o + KN + i];
    float4 t0 = *reinterpret_cast<const float4*>(&fjp[o + l * 4]);
    float4 t1 = *reinterpret_cast<const float4*>(&fjp[o + KN + l * 4]);
    fj0[0] += t0.x; fj0[1] += t0.y; fj0[2] += t0.z; fj0[3] += t0.w;
    fj1[0] += t1.x; fj1[1] += t1.y; fj1[2] += t1.z; fj1[3] += t1.w;
  }
  float e0[4], e1[4];
  const float NEGINF = -3.0e38f;
  float m0 = NEGINF, m1 = NEGINF;
  for (int e = 0; e < 4; ++e) {
    float v0 = fi0 + fj0[e], v1 = fi1 + fj1[e];
    v0 = v0 >= 0.f ? v0 : 0.2f * v0;
    v1 = v1 >= 0.f ? v1 : 0.2f * v1;
    e0[e] = v0; e1[e] = v1;
    if (msk[e]) { m0 = fmaxf(m0, v0); m1 = fmaxf(m1, v1); }
  }
  for (int off = 1; off < 64; off <<= 1) {
    m0 = fmaxf(m0, __shfl_xor(m0, off));
    m1 = fmaxf(m1, __shfl_xor(m1, off));
  }
  float p0[4], p1[4], s0 = 0.f, s1 = 0.f;
  for (int e = 0; e < 4; ++e) {
    p0[e] = msk[e] ? __expf(e0[e] - m0) : 0.f;
    p1[e] = msk[e] ? __expf(e1[e] - m1) : 0.f;
    s0 += p0[e]; s1 += p1[e];
  }
  for (int off = 1; off < 64; off <<= 1) {
    s0 += __shfl_xor(s0, off);
    s1 += __shfl_xor(s1, off);
  }
  float i0 = s0 > 0.f ? 1.f / s0 : 0.f;
  float i1 = s1 > 0.f ? 1.f / s1 : 0.f;
  ushort4 o;
  o.x = f2b(0.5f * (p0[0] * i0 + p1[0] * i1));
  o.y = f2b(0.5f * (p0[1] * i0 + p1[1] * i1));
  o.z = f2b(0.5f * (p0[2] * i0 + p1[2] * i1));
  o.w = f2b(0.5f * (p0[3] * i0 + p1[3] * i1));
  *reinterpret_cast<ushort4*>(&Pb[((size_t)b * KN + i) * KN + l * 4]) = o;
}

// ---------------- K4: y = Pbar[b] @ h[b] + x (bf16) + per-dtile LN partial stats
// block = (b, dt): 256 rows x 128 cols; hT read exactly once across grid
__global__ __launch_bounds__(512) void k_gemm_o(const ushort* __restrict__ Pb,
                                                const ushort* __restrict__ hT,
                                                const float* __restrict__ x,
                                                ushort* __restrict__ y,
                                                float* __restrict__ pstats) {
  __shared__ ushort As[2][8192];   // 256 x 32
  __shared__ ushort Bs[2][4096];   // 128 x 32
  __shared__ float red2[256][2][2];
  const int b = blockIdx.x;        // batch -> XCD-local (flat%8 == b%8)
  const int dt = blockIdx.y;       // d-tile 0..7
  const int tid = threadIdx.x;
  const int w = tid >> 6, lane = tid & 63;
  const int wm = (w >> 1) * 64;    // i-offset (0..192)
  const int wn = (w & 1) * 64;     // d-offset within 128
  const int r16 = lane & 15, kqi = lane >> 4;
  const ushort* PbB = Pb + (size_t)b * KN * KN;
  const ushort* hTB = hT + ((size_t)b * DD + dt * 128) * KN;
  f32x4 acc[4][4] = {};

  // staging helpers inline
  const int wb = tid & ~63;
  #define OSTAGE(buf, kt)                                                          \
    {                                                                              \
      for (int it = 0; it < 2; ++it) {                                             \
        int slot = it * 512 + tid;                                                 \
        int row = slot >> 2, kc = slot & 3;                                        \
        int kcs = kc ^ (((row >> 1) & 1) << 1);                                    \
        gload16(PbB + (size_t)row * KN + (kt) + kcs * 8,                           \
                As[buf] + (size_t)(it * 512 + wb) * 8);                            \
      }                                                                            \
      {                                                                            \
        int row = tid >> 2, kc = tid & 3;                                          \
        int kcs = kc ^ (((row >> 1) & 1) << 1);                                    \
        gload16(hTB + (size_t)row * KN + (kt) + kcs * 8,                           \
                Bs[buf] + (size_t)wb * 8);                                         \
      }                                                                            \
    }

  OSTAGE(0, 0);
  __syncthreads();
  for (int kt = 0; kt < KN; kt += 32) {
    int cur = (kt >> 5) & 1;
    if (kt + 32 < KN)
      OSTAGE(cur ^ 1, kt + 32);
    const ushort* Ac = As[cur];
    const ushort* Bc = Bs[cur];
    short8 af[4], bf[4];
    for (int mf = 0; mf < 4; ++mf) {
      int row = wm + mf * 16 + r16;
      af[mf] = *reinterpret_cast<const short8*>(Ac + (size_t)row * 32 + (kqi ^ (((row >> 1) & 1) << 1)) * 8);
    }
    for (int nf = 0; nf < 4; ++nf) {
      int row = wn + nf * 16 + r16;
      bf[nf] = *reinterpret_cast<const short8*>(Bc + (size_t)row * 32 + (kqi ^ (((row >> 1) & 1) << 1)) * 8);
    }
    for (int mf = 0; mf < 4; ++mf)
      for (int nf = 0; nf < 4; ++nf)
        acc[mf][nf] = __builtin_amdgcn_mfma_f32_16x16x32_bf16(af[mf], bf[nf], acc[mf][nf], 0, 0, 0);
    __syncthreads();
  }
  #undef OSTAGE

  // epilogue: residual + y write + per-row partial stats over this block's 128 cols
  const int g = lane >> 4;
  float ps[4][4] = {}, qs[4][4] = {};
  #pragma unroll
  for (int mf = 0; mf < 4; ++mf)
    #pragma unroll
    for (int nf = 0; nf < 4; ++nf) {
      int C = dt * 128 + wn + nf * 16 + r16;
      #pragma unroll
      for (int rr = 0; rr < 4; ++rr) {
        int i = wm + mf * 16 + g * 4 + rr;
        size_t gi = ((size_t)(b * KN + i)) * DD + C;
        float v = acc[mf][nf][rr] + x[gi];
        y[gi] = f2b(v);
        ps[mf][rr] += v; qs[mf][rr] += v * v;
      }
    }
  #pragma unroll
  for (int off = 1; off < 16; off <<= 1)
    #pragma unroll
    for (int mf = 0; mf < 4; ++mf)
      #pragma unroll
      for (int rr = 0; rr < 4; ++rr) {
        ps[mf][rr] += __shfl_xor(ps[mf][rr], off);
        qs[mf][rr] += __shfl_xor(qs[mf][rr], off);
      }
  if (r16 == 0) {
    #pragma unroll
    for (int mf = 0; mf < 4; ++mf)
      #pragma unroll
      for (int rr = 0; rr < 4; ++rr) {
        int i = wm + mf * 16 + g * 4 + rr;
        red2[i][w & 1][0] = ps[mf][rr];
        red2[i][w & 1][1] = qs[mf][rr];
      }
  }
  __syncthreads();
  if (tid < 256) {
    float S = red2[tid][0][0] + red2[tid][1][0];
    float Q = red2[tid][0][1] + red2[tid][1][1];
    size_t o = ((size_t)(dt * 64 + b) * KN + tid) * 2;
    pstats[o] = S;
    pstats[o + 1] = Q;
  }
}

// ---------------- K5: LN scale pass: out = (y - mu) * inv * gamma + beta
__global__ __launch_bounds__(256) void k_ln(const ushort* __restrict__ y,
                                            const float* __restrict__ pstats,
                                            const float* __restrict__ gamma,
                                            const float* __restrict__ beta,
                                            float* __restrict__ out) {
  int tid = threadIdx.x;
  size_t row = blockIdx.x;
  int b = (int)(row >> 8), i = (int)(row & 255);
  float S = 0.f, Q = 0.f;
  #pragma unroll
  for (int dt = 0; dt < 8; ++dt) {
    size_t o = ((size_t)(dt * 64 + b) * KN + i) * 2;
    S += pstats[o];
    Q += pstats[o + 1];
  }
  float mu = S * (1.0f / DD);
  float var = Q * (1.0f / DD) - mu * mu;
  float inv = rsqrtf(var + 1e-5f);
  ushort4 v = *reinterpret_cast<const ushort4*>(&y[row * DD + tid * 4]);
  float4 gm = *reinterpret_cast<const float4*>(&gamma[tid * 4]);
  float4 bt = *reinterpret_cast<const float4*>(&beta[tid * 4]);
  float4 o;
  o.x = (b2f(v.x) - mu) * inv * gm.x + bt.x;
  o.y = (b2f(v.y) - mu) * inv * gm.y + bt.y;
  o.z = (b2f(v.z) - mu) * inv * gm.z + bt.z;
  o.w = (b2f(v.w) - mu) * inv * gm.w + bt.w;
  *reinterpret_cast<float4*>(&out[row * DD + tid * 4]) = o;
}

extern "C" void kernel_launch(void* const* d_in, const int* in_sizes, int n_in,
                              void* d_out, int out_size, void* d_ws, size_t ws_size,
                              hipStream_t stream) {
  const float* x     = (const float*)d_in[0];
  const int*   adj   = (const int*)d_in[1];
  const float* W     = (const float*)d_in[2];
  const float* a     = (const float*)d_in[3];
  const float* gamma = (const float*)d_in[4];
  const float* beta  = (const float*)d_in[5];
  float* out = (float*)d_out;

  char* ws = (char*)d_ws;
  // Liveness-overlaid layout (NEED = 77856768 as proven available):
  //   [0, 2M):      WTb (wT->gemm_h); then fip/fjp (k_f->attn); then pstats (gemm_o->ln)
  //   [2M, 35.5M):  xb (conv->gemm_h); then y (gemm_o->ln)
  //   [35.5M, 69M): hT (gemm_h->gemm_o)
  //   [69M, 77.4M): Pb (attn->gemm_o)
  const size_t OFS_WT = 0;
  const size_t OFS_XB = 2097152;
  const size_t OFS_HT = 35651584;
  const size_t OFS_PB = 69206016;
  const size_t NEED   = 77856768;
  if (ws_size < NEED) return;

  ushort* WTb   = (ushort*)(ws + OFS_WT);
  float*  fip   = (float*)(ws + OFS_WT);            // 512 KB, after WTb dead
  float*  fjp   = (float*)(ws + OFS_WT + 524288);   // 512 KB
  float*  pst   = (float*)(ws + OFS_WT);            // 1 MB, after fip/fjp dead
  ushort* xb    = (ushort*)(ws + OFS_XB);
  ushort* y     = (ushort*)(ws + OFS_XB);           // aliases xb (dead after gemm_h)
  ushort* hT    = (ushort*)(ws + OFS_HT);
  ushort* Pb    = (ushort*)(ws + OFS_PB);

  k_conv<<<2048, 256, 0, stream>>>(x, xb);
  k_wT<<<dim3(32, 32), dim3(32, 8), 0, stream>>>(W, WTb);
  k_gemm_h<<<dim3(128, 8), 256, 0, stream>>>(xb, WTb, hT);
  k_f<<<dim3(64, 4), 256, 0, stream>>>(hT, a, fip, fjp);
  k_attn<<<4096, 256, 0, stream>>>(fip, fjp, adj, Pb);
  k_gemm_o<<<dim3(64, 8), 512, 0, stream>>>(Pb, hT, x, y, pst);
  k_ln<<<16384, 256, 0, stream>>>(y, pst, gamma, beta, out);
}

// Round 5
// 140.582 us; speedup vs baseline: 1.3647x; 1.0228x over previous
//
#include <hip/hip_runtime.h>
#include <hip/hip_bf16.h>

#define KN 256
#define DD 1024
#define HH 2

typedef __attribute__((ext_vector_type(8))) short short8;
typedef __attribute__((ext_vector_type(4))) float f32x4;

__device__ __forceinline__ ushort f2b(float f) {
  union { float f; unsigned u; } v; v.f = f;
  unsigned u = v.u;
  return (ushort)((u + 0x7fffu + ((u >> 16) & 1u)) >> 16);
}
__device__ __forceinline__ float b2f(ushort h) {
  union { unsigned u; float f; } v; v.u = ((unsigned)h) << 16;
  return v.f;
}
__device__ __forceinline__ void gload16(const ushort* g, ushort* l) {
  __builtin_amdgcn_global_load_lds(
      (const __attribute__((address_space(1))) void*)g,
      (__attribute__((address_space(3))) void*)l, 16, 0, 0);
}

// ---------------- K-conv: x f32 -> xb bf16
__global__ __launch_bounds__(256) void k_conv(const float* __restrict__ x,
                                              ushort* __restrict__ xb) {
  int c0 = blockIdx.x * 256 + threadIdx.x;
  for (int it = 0; it < 4; ++it) {
    size_t i = ((size_t)c0 + (size_t)it * 524288) * 8;
    float4 v0 = *reinterpret_cast<const float4*>(&x[i]);
    float4 v1 = *reinterpret_cast<const float4*>(&x[i + 4]);
    short8 o;
    o[0] = (short)f2b(v0.x); o[1] = (short)f2b(v0.y);
    o[2] = (short)f2b(v0.z); o[3] = (short)f2b(v0.w);
    o[4] = (short)f2b(v1.x); o[5] = (short)f2b(v1.y);
    o[6] = (short)f2b(v1.z); o[7] = (short)f2b(v1.w);
    *reinterpret_cast<short8*>(&xb[i]) = o;
  }
}

// ---------------- K0: W (DxD f32) -> WTb (DxD bf16, transposed)
__global__ __launch_bounds__(256) void k_wT(const float* __restrict__ W, ushort* __restrict__ WTb) {
  __shared__ float t[32][33];
  int tx = threadIdx.x, ty = threadIdx.y;
  int x = blockIdx.x * 32 + tx;
  int y0 = blockIdx.y * 32 + ty;
  for (int i = 0; i < 32; i += 8)
    t[ty + i][tx] = W[(size_t)(y0 + i) * DD + x];
  __syncthreads();
  int xo = blockIdx.y * 32 + tx;
  int yo = blockIdx.x * 32 + ty;
  for (int i = 0; i < 32; i += 8)
    WTb[(size_t)(yo + i) * DD + xo] = f2b(t[tx][ty + i]);
}

// ---------------- K1: h = xb @ W -> write TRANSPOSED hT[b][d][j]
// counted-vmcnt depth-2 pipeline (T3/T4 minimum recipe)
__device__ __forceinline__ void gh_stage(const ushort* gA0, const ushort* gB0, int kt,
                                         ushort* As, ushort* Bs, int tid) {
  int wb = tid & ~63;
  #pragma unroll
  for (int it = 0; it < 2; ++it) {
    int slot = it * 256 + tid;
    int row = slot >> 2, kc = slot & 3;
    gload16(gA0 + (size_t)row * DD + kt + kc * 8, As + (size_t)(it * 256 + wb) * 8);
    gload16(gB0 + (size_t)row * DD + kt + kc * 8, Bs + (size_t)(it * 256 + wb) * 8);
  }
}

__global__ __launch_bounds__(256) void k_gemm_h(const ushort* __restrict__ xb,
                                                const ushort* __restrict__ WTb,
                                                ushort* __restrict__ hT) {
  __shared__ ushort As[2][4096];
  __shared__ ushort Bs[2][4096];
  const int tid = threadIdx.x;
  const int bm = blockIdx.x;   // 0..127 (row tile, batch-half)
  const int bn = blockIdx.y;   // 0..7
  const int w = tid >> 6, lane = tid & 63;
  const int wm = (w >> 1) * 64, wn = (w & 1) * 64;
  const int r16 = lane & 15, kqi = lane >> 4;
  const ushort* gA0 = xb + (size_t)(bm * 128) * DD;
  const ushort* gB0 = WTb + (size_t)(bn * 128) * DD;
  f32x4 acc[4][4] = {};

  gh_stage(gA0, gB0, 0, As[0], Bs[0], tid);
  gh_stage(gA0, gB0, 32, As[1], Bs[1], tid);
  for (int it = 0; it < 32; ++it) {
    const int cur = it & 1;
    // wait for tile `it`'s 4 loads (tile it+1's 4 remain in flight)
    if (it < 31) asm volatile("s_waitcnt vmcnt(4)" ::: "memory");
    else         asm volatile("s_waitcnt vmcnt(0)" ::: "memory");
    __builtin_amdgcn_s_barrier();
    __builtin_amdgcn_sched_barrier(0);
    const ushort* Ac = As[cur];
    const ushort* Bc = Bs[cur];
    short8 af[4], bf[4];
    #pragma unroll
    for (int mf = 0; mf < 4; ++mf) {
      int row = wm + mf * 16 + r16;
      af[mf] = *reinterpret_cast<const short8*>(Ac + (size_t)row * 32 + kqi * 8);
    }
    #pragma unroll
    for (int nf = 0; nf < 4; ++nf) {
      int row = wn + nf * 16 + r16;
      bf[nf] = *reinterpret_cast<const short8*>(Bc + (size_t)row * 32 + kqi * 8);
    }
    #pragma unroll
    for (int mf = 0; mf < 4; ++mf)
      #pragma unroll
      for (int nf = 0; nf < 4; ++nf)
        acc[mf][nf] = __builtin_amdgcn_mfma_f32_16x16x32_bf16(af[mf], bf[nf], acc[mf][nf], 0, 0, 0);
    __builtin_amdgcn_sched_barrier(0);
    __builtin_amdgcn_s_barrier();
    if (it < 30)
      gh_stage(gA0, gB0, (it + 2) * 32, As[cur], Bs[cur], tid);
  }
  // transposed epilogue: 4 acc regs = 4 consecutive j -> one 8B store
  const int b = bm >> 1;
  const int j0base = (bm & 1) * 128 + wm;
  #pragma unroll
  for (int mf = 0; mf < 4; ++mf) {
    int j0 = j0base + mf * 16 + (lane >> 4) * 4;
    #pragma unroll
    for (int nf = 0; nf < 4; ++nf) {
      int C = bn * 128 + wn + nf * 16 + r16;
      ushort4 o;
      o.x = f2b(acc[mf][nf][0]); o.y = f2b(acc[mf][nf][1]);
      o.z = f2b(acc[mf][nf][2]); o.w = f2b(acc[mf][nf][3]);
      *reinterpret_cast<ushort4*>(&hT[((size_t)b * DD + C) * KN + j0]) = o;
    }
  }
}

// ---------------- K2: f partials from hT (axpy form). block=(b, dq): 256 d-rows
__global__ __launch_bounds__(256) void k_f(const ushort* __restrict__ hT,
                                           const float* __restrict__ a,
                                           float* __restrict__ fip, float* __restrict__ fjp) {
  __shared__ float als[4][256];
  int b = blockIdx.x, dq = blockIdx.y;
  int tid = threadIdx.x;
  for (int v = 0; v < 4; ++v) als[v][tid] = a[v * DD + dq * 256 + tid];
  __syncthreads();
  const ushort* base = hT + ((size_t)b * DD + dq * 256) * KN + tid;
  float a0 = 0.f, a1 = 0.f, a2 = 0.f, a3 = 0.f;
  #pragma unroll 8
  for (int d = 0; d < 256; ++d) {
    float hv = b2f(base[(size_t)d * KN]);
    a0 += hv * als[0][d];
    a1 += hv * als[1][d];
    a2 += hv * als[2][d];
    a3 += hv * als[3][d];
  }
  size_t o = ((size_t)(dq * 64 + b) * HH) * KN + tid;
  fip[o] = a0;        // head0 src
  fjp[o] = a1;        // head0 dst
  fip[o + KN] = a2;   // head1 src
  fjp[o + KN] = a3;   // head1 dst
}

// ---------------- K3: masked leaky softmax, head-mean -> Pbar bf16 (wave per row)
__global__ __launch_bounds__(256) void k_attn(const float* __restrict__ fip, const float* __restrict__ fjp,
                                              const int* __restrict__ adj, ushort* __restrict__ Pb) {
  int w = threadIdx.x >> 6, l = threadIdx.x & 63;
  int gw = blockIdx.x * 4 + w;
  int b = gw >> 8, i = gw & 255;
  int4 am = *reinterpret_cast<const int4*>(adj + i * KN + l * 4);
  int msk[4] = { am.x, am.y, am.z, am.w };
  float fi0 = 0.f, fi1 = 0.f;
  float fj0[4] = {0.f, 0.f, 0.f, 0.f}, fj1[4] = {0.f, 0.f, 0.f, 0.f};
  for (int dq = 0; dq < 4; ++dq) {
    size_t o = ((size_t)(dq * 64 + b) * HH) * KN;
    fi0 += fip[o + i];
    fi1 += fip[o + KN + i];
    float4 t0 = *reinterpret_cast<const float4*>(&fjp[o + l * 4]);
    float4 t1 = *reinterpret_cast<const float4*>(&fjp[o + KN + l * 4]);
    fj0[0] += t0.x; fj0[1] += t0.y; fj0[2] += t0.z; fj0[3] += t0.w;
    fj1[0] += t1.x; fj1[1] += t1.y; fj1[2] += t1.z; fj1[3] += t1.w;
  }
  float e0[4], e1[4];
  const float NEGINF = -3.0e38f;
  float m0 = NEGINF, m1 = NEGINF;
  for (int e = 0; e < 4; ++e) {
    float v0 = fi0 + fj0[e], v1 = fi1 + fj1[e];
    v0 = v0 >= 0.f ? v0 : 0.2f * v0;
    v1 = v1 >= 0.f ? v1 : 0.2f * v1;
    e0[e] = v0; e1[e] = v1;
    if (msk[e]) { m0 = fmaxf(m0, v0); m1 = fmaxf(m1, v1); }
  }
  for (int off = 1; off < 64; off <<= 1) {
    m0 = fmaxf(m0, __shfl_xor(m0, off));
    m1 = fmaxf(m1, __shfl_xor(m1, off));
  }
  float p0[4], p1[4], s0 = 0.f, s1 = 0.f;
  for (int e = 0; e < 4; ++e) {
    p0[e] = msk[e] ? __expf(e0[e] - m0) : 0.f;
    p1[e] = msk[e] ? __expf(e1[e] - m1) : 0.f;
    s0 += p0[e]; s1 += p1[e];
  }
  for (int off = 1; off < 64; off <<= 1) {
    s0 += __shfl_xor(s0, off);
    s1 += __shfl_xor(s1, off);
  }
  float i0 = s0 > 0.f ? 1.f / s0 : 0.f;
  float i1 = s1 > 0.f ? 1.f / s1 : 0.f;
  ushort4 o;
  o.x = f2b(0.5f * (p0[0] * i0 + p1[0] * i1));
  o.y = f2b(0.5f * (p0[1] * i0 + p1[1] * i1));
  o.z = f2b(0.5f * (p0[2] * i0 + p1[2] * i1));
  o.w = f2b(0.5f * (p0[3] * i0 + p1[3] * i1));
  *reinterpret_cast<ushort4*>(&Pb[((size_t)b * KN + i) * KN + l * 4]) = o;
}

// ---------------- K4: y = Pbar[b] @ h[b] + x (bf16) + per-dtile LN partial stats
// counted-vmcnt depth-2 pipeline; block = (b, dt); hT read exactly once
__global__ __launch_bounds__(512) void k_gemm_o(const ushort* __restrict__ Pb,
                                                const ushort* __restrict__ hT,
                                                const float* __restrict__ x,
                                                const ushort* __restrict__ xb,
                                                int use_xb,
                                                ushort* __restrict__ y,
                                                float* __restrict__ pstats) {
  __shared__ ushort As[2][8192];   // 256 x 32
  __shared__ ushort Bs[2][4096];   // 128 x 32
  __shared__ float red2[256][2][2];
  const int b = blockIdx.x;        // batch -> XCD-local (flat%8 == b%8)
  const int dt = blockIdx.y;       // d-tile 0..7
  const int tid = threadIdx.x;
  const int w = tid >> 6, lane = tid & 63;
  const int wm = (w >> 1) * 64;    // i-offset (0..192)
  const int wn = (w & 1) * 64;     // d-offset within 128
  const int r16 = lane & 15, kqi = lane >> 4;
  const ushort* PbB = Pb + (size_t)b * KN * KN;
  const ushort* hTB = hT + ((size_t)b * DD + dt * 128) * KN;
  f32x4 acc[4][4] = {};
  const int wb = tid & ~63;

  #define OSTAGE(buf, kt)                                                          \
    {                                                                              \
      _Pragma("unroll")                                                            \
      for (int s = 0; s < 2; ++s) {                                                \
        int slot = s * 512 + tid;                                                  \
        int row = slot >> 2, kc = slot & 3;                                        \
        gload16(PbB + (size_t)row * KN + (kt) + kc * 8,                            \
                As[buf] + (size_t)(s * 512 + wb) * 8);                             \
      }                                                                            \
      {                                                                            \
        int row = tid >> 2, kc = tid & 3;                                          \
        gload16(hTB + (size_t)row * KN + (kt) + kc * 8,                            \
                Bs[buf] + (size_t)wb * 8);                                         \
      }                                                                            \
    }

  OSTAGE(0, 0);
  OSTAGE(1, 32);
  for (int it8 = 0; it8 < 8; ++it8) {
    const int cur = it8 & 1;
    if (it8 < 7) asm volatile("s_waitcnt vmcnt(3)" ::: "memory");
    else         asm volatile("s_waitcnt vmcnt(0)" ::: "memory");
    __builtin_amdgcn_s_barrier();
    __builtin_amdgcn_sched_barrier(0);
    const ushort* Ac = As[cur];
    const ushort* Bc = Bs[cur];
    short8 af[4], bf[4];
    #pragma unroll
    for (int mf = 0; mf < 4; ++mf) {
      int row = wm + mf * 16 + r16;
      af[mf] = *reinterpret_cast<const short8*>(Ac + (size_t)row * 32 + kqi * 8);
    }
    #pragma unroll
    for (int nf = 0; nf < 4; ++nf) {
      int row = wn + nf * 16 + r16;
      bf[nf] = *reinterpret_cast<const short8*>(Bc + (size_t)row * 32 + kqi * 8);
    }
    #pragma unroll
    for (int mf = 0; mf < 4; ++mf)
      #pragma unroll
      for (int nf = 0; nf < 4; ++nf)
        acc[mf][nf] = __builtin_amdgcn_mfma_f32_16x16x32_bf16(af[mf], bf[nf], acc[mf][nf], 0, 0, 0);
    __builtin_amdgcn_sched_barrier(0);
    __builtin_amdgcn_s_barrier();
    if (it8 < 6)
      OSTAGE(cur, (it8 + 2) * 32);
  }
  #undef OSTAGE

  // epilogue: residual + y write + per-row partial stats over this block's 128 cols
  const int g = lane >> 4;
  float ps[4][4] = {}, qs[4][4] = {};
  #pragma unroll
  for (int mf = 0; mf < 4; ++mf)
    #pragma unroll
    for (int nf = 0; nf < 4; ++nf) {
      int C = dt * 128 + wn + nf * 16 + r16;
      #pragma unroll
      for (int rr = 0; rr < 4; ++rr) {
        int i = wm + mf * 16 + g * 4 + rr;
        size_t gi = ((size_t)(b * KN + i)) * DD + C;
        float rv = use_xb ? b2f(xb[gi]) : x[gi];
        float v = acc[mf][nf][rr] + rv;
        y[gi] = f2b(v);
        ps[mf][rr] += v; qs[mf][rr] += v * v;
      }
    }
  #pragma unroll
  for (int off = 1; off < 16; off <<= 1)
    #pragma unroll
    for (int mf = 0; mf < 4; ++mf)
      #pragma unroll
      for (int rr = 0; rr < 4; ++rr) {
        ps[mf][rr] += __shfl_xor(ps[mf][rr], off);
        qs[mf][rr] += __shfl_xor(qs[mf][rr], off);
      }
  if (r16 == 0) {
    #pragma unroll
    for (int mf = 0; mf < 4; ++mf)
      #pragma unroll
      for (int rr = 0; rr < 4; ++rr) {
        int i = wm + mf * 16 + g * 4 + rr;
        red2[i][w & 1][0] = ps[mf][rr];
        red2[i][w & 1][1] = qs[mf][rr];
      }
  }
  __syncthreads();
  if (tid < 256) {
    float S = red2[tid][0][0] + red2[tid][1][0];
    float Q = red2[tid][0][1] + red2[tid][1][1];
    size_t o = ((size_t)(dt * 64 + b) * KN + tid) * 2;
    pstats[o] = S;
    pstats[o + 1] = Q;
  }
}

// ---------------- K5: LN scale pass: out = (y - mu) * inv * gamma + beta
__global__ __launch_bounds__(256) void k_ln(const ushort* __restrict__ y,
                                            const float* __restrict__ pstats,
                                            const float* __restrict__ gamma,
                                            const float* __restrict__ beta,
                                            float* __restrict__ out) {
  int tid = threadIdx.x;
  size_t row = blockIdx.x;
  int b = (int)(row >> 8), i = (int)(row & 255);
  float S = 0.f, Q = 0.f;
  #pragma unroll
  for (int dt = 0; dt < 8; ++dt) {
    size_t o = ((size_t)(dt * 64 + b) * KN + i) * 2;
    S += pstats[o];
    Q += pstats[o + 1];
  }
  float mu = S * (1.0f / DD);
  float var = Q * (1.0f / DD) - mu * mu;
  float inv = rsqrtf(var + 1e-5f);
  ushort4 v = *reinterpret_cast<const ushort4*>(&y[row * DD + tid * 4]);
  float4 gm = *reinterpret_cast<const float4*>(&gamma[tid * 4]);
  float4 bt = *reinterpret_cast<const float4*>(&beta[tid * 4]);
  float4 o;
  o.x = (b2f(v.x) - mu) * inv * gm.x + bt.x;
  o.y = (b2f(v.y) - mu) * inv * gm.y + bt.y;
  o.z = (b2f(v.z) - mu) * inv * gm.z + bt.z;
  o.w = (b2f(v.w) - mu) * inv * gm.w + bt.w;
  *reinterpret_cast<float4*>(&out[row * DD + tid * 4]) = o;
}

extern "C" void kernel_launch(void* const* d_in, const int* in_sizes, int n_in,
                              void* d_out, int out_size, void* d_ws, size_t ws_size,
                              hipStream_t stream) {
  const float* x     = (const float*)d_in[0];
  const int*   adj   = (const int*)d_in[1];
  const float* W     = (const float*)d_in[2];
  const float* a     = (const float*)d_in[3];
  const float* gamma = (const float*)d_in[4];
  const float* beta  = (const float*)d_in[5];
  float* out = (float*)d_out;

  char* ws = (char*)d_ws;
  // Base layout (77.86 MB):
  //   [0, 2M):      WTb (wT->gemm_h); then fip/fjp (k_f->attn); then pstats (gemm_o->ln)
  //   [2M, 35.5M):  xb (conv->gemm_h); then y (gemm_o->ln)     [base mode]
  //   [35.5M, 69M): hT (gemm_h->gemm_o)
  //   [69M, 77.4M): Pb (attn->gemm_o)
  // Big layout (111.4 MB): xb stays live through gemm_o (bf16 residual);
  //   y at [77.86M, 111.4M).
  const size_t OFS_WT = 0;
  const size_t OFS_XB = 2097152;
  const size_t OFS_HT = 35651584;
  const size_t OFS_PB = 69206016;
  const size_t NEED     = 77856768;
  const size_t NEED_BIG = 111411200;
  if (ws_size < NEED) return;
  const int use_xb = (ws_size >= NEED_BIG) ? 1 : 0;

  ushort* WTb   = (ushort*)(ws + OFS_WT);
  float*  fip   = (float*)(ws + OFS_WT);            // 512 KB, after WTb dead
  float*  fjp   = (float*)(ws + OFS_WT + 524288);   // 512 KB
  float*  pst   = (float*)(ws + OFS_WT);            // 1 MB, after fip/fjp dead
  ushort* xb    = (ushort*)(ws + OFS_XB);
  ushort* hT    = (ushort*)(ws + OFS_HT);
  ushort* Pb    = (ushort*)(ws + OFS_PB);
  ushort* y     = use_xb ? (ushort*)(ws + NEED) : (ushort*)(ws + OFS_XB);

  k_conv<<<2048, 256, 0, stream>>>(x, xb);
  k_wT<<<dim3(32, 32), dim3(32, 8), 0, stream>>>(W, WTb);
  k_gemm_h<<<dim3(128, 8), 256, 0, stream>>>(xb, WTb, hT);
  k_f<<<dim3(64, 4), 256, 0, stream>>>(hT, a, fip, fjp);
  k_attn<<<4096, 256, 0, stream>>>(fip, fjp, adj, Pb);
  k_gemm_o<<<dim3(64, 8), 512, 0, stream>>>(Pb, hT, x, xb, use_xb, y, pst);
  k_ln<<<16384, 256, 0, stream>>>(y, pst, gamma, beta, out);
}